// Round 11
// baseline (2195.500 us; speedup 1.0000x reference)
//
#include <hip/hip_runtime.h>
#include <hip/hip_bf16.h>

// Problem: B=32, L=2048, H=1024, K=3H=3072, M=B*L=65536
// ref: t = trg @ fc_w^T + fc_b  [M, H]
//      norm1 = ||t||_2 over H   [B, L]
//      w = softmax(norm1, axis=L)
//      summ = sum_l w * t = fc_w @ (sum_l w*trg) + fc_b   (since sum_l w == 1)
// out = concat(summ [32*1024], norm1 [32*2048]) fp32

#define B_ 32
#define L_ 2048
#define H_ 1024
#define K_ 3072
#define M_ 65536

typedef __attribute__((ext_vector_type(8))) short short8;
typedef __attribute__((ext_vector_type(4))) float floatx4;

__device__ __forceinline__ unsigned int pack_bf16x2(float a, float b) {
    __hip_bfloat162 h = __float22bfloat162_rn(make_float2(a, b));
    return *reinterpret_cast<unsigned int*>(&h);
}

__device__ __forceinline__ float bf2f(unsigned short u) {
    return __uint_as_float(((unsigned int)u) << 16);
}

// async global->LDS, 16B per lane; lds dest is wave-uniform base + lane*16
__device__ __forceinline__ void gl_lds16(const unsigned short* g, unsigned short* l) {
    __builtin_amdgcn_global_load_lds(
        (const __attribute__((address_space(1))) unsigned int*)g,
        (__attribute__((address_space(3))) unsigned int*)l, 16, 0, 0);
}

// ---------------- K0: fp32 -> bf16 convert (grid-stride, 8 elems/thread/iter) --------
__global__ void __launch_bounds__(256) convert_bf16_kernel(const float* __restrict__ in,
                                                           unsigned short* __restrict__ out,
                                                           int n8) {
    int i = blockIdx.x * blockDim.x + threadIdx.x;
    const int stride = gridDim.x * blockDim.x;
    for (; i < n8; i += stride) {
        const float4* pp = (const float4*)in + (size_t)i * 2;
        float4 a = pp[0], b = pp[1];
        uint4 r;
        r.x = pack_bf16x2(a.x, a.y);
        r.y = pack_bf16x2(a.z, a.w);
        r.z = pack_bf16x2(b.x, b.y);
        r.w = pack_bf16x2(b.z, b.w);
        ((uint4*)out)[i] = r;
    }
}

// ---------------- K1 (primary): counted-vmcnt pipelined bf16 GEMM + fused row-sumsq --
// Tile 128x256, BK=64, 8 waves (2M x 4N), wave-tile 64x64.
// A: triple-buffered LDS via global_load_lds (16KB/buf), XOR-swizzled 128B rows
//    (conflict-free ds_read_b128), staged 2 K-tiles ahead.
// B: fc_w slab (1.5MB) is XCD-L2-resident -> loaded straight to registers,
//    double-buffered one K-tile ahead. No LDS, no barrier coupling for B.
// Sync per K-tile: s_waitcnt vmcnt(2) + raw s_barrier (never vmcnt(0) in loop).
// Issue order per tile (pinned by sched_barrier): B(t+1) regs -> A(t+2) stages.
#define NT_ 48  // K / 64

__global__ void __launch_bounds__(512, 2) gemm_norm_bf_kernel(
        const unsigned short* __restrict__ A,   // trg bf16 [M_, K_]
        const unsigned short* __restrict__ Bw,  // fcw bf16 [H_, K_]
        const float* __restrict__ fcb,          // [H_]
        float* __restrict__ normsq) {
    __shared__ unsigned short As[3 * 128 * 64];  // 3 x 16KB A buffers

    const int tid = threadIdx.x;
    const int bid = blockIdx.x;
    // bijective XCD swizzle: 2048 = 8 xcd x 256; the 4 N-siblings of an M-block
    // are adjacent in seq -> share A via that XCD's L2.
    const int xcd  = bid & 7;
    const int seq  = bid >> 3;
    const int mblk = xcd * 64 + (seq >> 2);   // 0..511
    const int nblk = seq & 3;                 // 0..3
    const int R0 = mblk * 128;
    const int N0 = nblk * 256;

    const int wv = tid >> 6, lane = tid & 63;
    const int wr = wv >> 2, wc = wv & 3;      // 2M x 4N wave grid
    const int q = lane >> 4, ln = lane & 15;

    // ---- A staging: this wave stages tile rows [wv*16, wv*16+16) as two 8-row
    // 1KB chunks. LDS dest is linear; the XOR swizzle is applied by permuting the
    // per-lane GLOBAL source chunk (rule: both-sides-or-neither).
    const int rin = lane >> 3;                // row within 8-row chunk
    const int slg = (lane & 7) ^ rin;         // logical 16B slot this lane must fetch
    const unsigned short* ag0 = A + (size_t)(R0 + wv * 16 + rin) * K_ + slg * 8;
    const unsigned short* ag1 = ag0 + (size_t)8 * K_;
    unsigned short* al = As + wv * 1024;      // chunk0 dest (buf0); +512 chunk1; +8192/buf

    // ---- B fragment pointers: row = N0 + wc*64 + ni*16 + ln, 16B chunk q*8
    const unsigned short* bg0 = Bw + (size_t)(N0 + wc * 64 + ln) * K_ + q * 8;
    const unsigned short* bg1 = bg0 + (size_t)16 * K_;
    const unsigned short* bg2 = bg0 + (size_t)32 * K_;
    const unsigned short* bg3 = bg0 + (size_t)48 * K_;

    // ---- A fragment read bases (kk=0/1): row = wr*64 + mi*16 + ln,
    // phys slot = (kk*4+q) ^ (row&7); row&7 == ln&7 here.
    const int arow = wr * 64 + ln;
    const unsigned short* Af0 = As + arow * 64 + ((q ^ (ln & 7)) * 8);
    const unsigned short* Af1 = As + arow * 64 + (((4 + q) ^ (ln & 7)) * 8);

    floatx4 acc[4][4] = {};
    short8 bf[2][4][2];

    // ---- prologue: issue order B(0) x8, then A(0) x2, A(1) x2 (FIFO for vmcnt(2))
    bf[0][0][0] = *(const short8*)(bg0);
    bf[0][0][1] = *(const short8*)(bg0 + 32);
    bf[0][1][0] = *(const short8*)(bg1);
    bf[0][1][1] = *(const short8*)(bg1 + 32);
    bf[0][2][0] = *(const short8*)(bg2);
    bf[0][2][1] = *(const short8*)(bg2 + 32);
    bf[0][3][0] = *(const short8*)(bg3);
    bf[0][3][1] = *(const short8*)(bg3 + 32);
    __builtin_amdgcn_sched_barrier(0);
    gl_lds16(ag0, al);                       // A(0) chunk0 -> buf0
    gl_lds16(ag1, al + 512);                 // A(0) chunk1
    gl_lds16(ag0 + 64, al + 8192);           // A(1) chunk0 -> buf1
    gl_lds16(ag1 + 64, al + 8192 + 512);     // A(1) chunk1
    __builtin_amdgcn_sched_barrier(0);

#define MFMA4(MI, AV, KKI)                                                              \
    acc[MI][0] = __builtin_amdgcn_mfma_f32_16x16x32_bf16(AV, bf[cur][0][KKI], acc[MI][0], 0, 0, 0); \
    acc[MI][1] = __builtin_amdgcn_mfma_f32_16x16x32_bf16(AV, bf[cur][1][KKI], acc[MI][1], 0, 0, 0); \
    acc[MI][2] = __builtin_amdgcn_mfma_f32_16x16x32_bf16(AV, bf[cur][2][KKI], acc[MI][2], 0, 0, 0); \
    acc[MI][3] = __builtin_amdgcn_mfma_f32_16x16x32_bf16(AV, bf[cur][3][KKI], acc[MI][3], 0, 0, 0);

    for (int it = 0; it < 8; ++it) {
#pragma unroll
        for (int u = 0; u < 6; ++u) {
            const int t   = it * 6 + u;
            const int buf = u % 3;          // static after unroll (it*6 % 3 == 0)
            const int cur = u & 1;          // static after unroll (it*6 even)
            const int nxt = cur ^ 1;

            // counted drain: guarantees A(t) (all older) + B(t) landed for MY wave,
            // leaves A(t+1)'s 2 chunk loads in flight. Barrier -> all waves' A(t) in LDS.
            asm volatile("s_waitcnt vmcnt(2)" ::: "memory");
            __builtin_amdgcn_s_barrier();

            // B(t+1) fragment loads (registers; full K-tile of latency to land)
            if (t < 47) {
                const int ko = (t + 1) * 64;
                bf[nxt][0][0] = *(const short8*)(bg0 + ko);
                bf[nxt][0][1] = *(const short8*)(bg0 + ko + 32);
                bf[nxt][1][0] = *(const short8*)(bg1 + ko);
                bf[nxt][1][1] = *(const short8*)(bg1 + ko + 32);
                bf[nxt][2][0] = *(const short8*)(bg2 + ko);
                bf[nxt][2][1] = *(const short8*)(bg2 + ko + 32);
                bf[nxt][3][0] = *(const short8*)(bg3 + ko);
                bf[nxt][3][1] = *(const short8*)(bg3 + ko + 32);
            }
            __builtin_amdgcn_sched_barrier(0);  // keep B issue above A stages (FIFO order)

            // ---- phase 0 (kk=0): stage A(t+2) chunk0, read 4 A-frags, 16 MFMA
            if (t < 46) gl_lds16(ag0 + (t + 2) * 64, al + ((u + 2) % 3) * 8192);
            {
                const unsigned short* af = Af0 + buf * 8192;
                short8 a0 = *(const short8*)(af);
                short8 a1 = *(const short8*)(af + 1024);
                short8 a2 = *(const short8*)(af + 2048);
                short8 a3 = *(const short8*)(af + 3072);
                __builtin_amdgcn_s_setprio(1);
                MFMA4(0, a0, 0)
                MFMA4(1, a1, 0)
                MFMA4(2, a2, 0)
                MFMA4(3, a3, 0)
                __builtin_amdgcn_s_setprio(0);
            }
            // ---- phase 1 (kk=1): stage A(t+2) chunk1, read 4 A-frags, 16 MFMA
            if (t < 46) gl_lds16(ag1 + (t + 2) * 64, al + ((u + 2) % 3) * 8192 + 512);
            {
                const unsigned short* af = Af1 + buf * 8192;
                short8 a0 = *(const short8*)(af);
                short8 a1 = *(const short8*)(af + 1024);
                short8 a2 = *(const short8*)(af + 2048);
                short8 a3 = *(const short8*)(af + 3072);
                __builtin_amdgcn_s_setprio(1);
                MFMA4(0, a0, 1)
                MFMA4(1, a1, 1)
                MFMA4(2, a2, 1)
                MFMA4(3, a3, 1)
                __builtin_amdgcn_s_setprio(0);
            }
        }
    }
#undef MFMA4

    // epilogue: add bias, per-row sum of squares over this block's 256 cols
    // D layout: col = ln, row = q*4 + reg
    float bz[4];
#pragma unroll
    for (int ni = 0; ni < 4; ++ni) bz[ni] = fcb[N0 + wc * 64 + ni * 16 + ln];

    float* nsq = normsq + R0 + wr * 64;
#pragma unroll
    for (int mi = 0; mi < 4; ++mi) {
#pragma unroll
        for (int r = 0; r < 4; ++r) {
            float s = 0.0f;
#pragma unroll
            for (int ni = 0; ni < 4; ++ni) {
                float v = acc[mi][ni][r] + bz[ni];
                s += v * v;
            }
            s += __shfl_xor(s, 1);
            s += __shfl_xor(s, 2);
            s += __shfl_xor(s, 4);
            s += __shfl_xor(s, 8);
            if (ln == 0) atomicAdd(&nsq[mi * 16 + q * 4 + r], s);
        }
    }
}

// ---------------- K1 (fallback): fp32-input GEMM with in-kernel convert -------------
#define LDST 40
__global__ void __launch_bounds__(256) gemm_norm_f32_kernel(const float* __restrict__ trg,
                                                            const float* __restrict__ fcw,
                                                            const float* __restrict__ fcb,
                                                            float* __restrict__ normsq) {
    __shared__ unsigned short As[128 * LDST];
    __shared__ unsigned short Bs[128 * LDST];

    const int tid  = threadIdx.x;
    const int bid  = blockIdx.x;
    const int group  = bid >> 6;
    const int lane64 = bid & 63;
    const int nblk   = lane64 >> 3;
    const int mblk   = group * 8 + (lane64 & 7);
    const int R0   = mblk * 128;
    const int N0   = nblk * 128;
    const int wv   = tid >> 6;
    const int lane = tid & 63;
    const int wr   = wv >> 1;
    const int wc   = wv & 1;
    const int q    = lane >> 4;
    const int ln   = lane & 15;

    floatx4 acc[4][4] = {};

    const int srow = tid >> 3;
    const int skc  = tid & 7;
    const float* ap = trg + (size_t)(R0 + srow) * K_ + skc * 4;
    const float* bp = fcw + (size_t)(N0 + srow) * K_ + skc * 4;
    unsigned short* AsW = &As[srow * LDST + skc * 4];
    unsigned short* BsW = &Bs[srow * LDST + skc * 4];

    const unsigned short* Af = &As[(wr * 64 + ln) * LDST + q * 8];
    const unsigned short* Bf = &Bs[(wc * 64 + ln) * LDST + q * 8];

    float4 ra[4], rb[4];
#pragma unroll
    for (int s = 0; s < 4; ++s) {
        ra[s] = *(const float4*)(ap + (size_t)(s * 32) * K_);
        rb[s] = *(const float4*)(bp + (size_t)(s * 32) * K_);
    }

    for (int step = 0; step < 96; ++step) {
        __syncthreads();
#pragma unroll
        for (int s = 0; s < 4; ++s) {
            uint2 ua, ub;
            ua.x = pack_bf16x2(ra[s].x, ra[s].y);
            ua.y = pack_bf16x2(ra[s].z, ra[s].w);
            ub.x = pack_bf16x2(rb[s].x, rb[s].y);
            ub.y = pack_bf16x2(rb[s].z, rb[s].w);
            *(uint2*)(AsW + s * 32 * LDST) = ua;
            *(uint2*)(BsW + s * 32 * LDST) = ub;
        }
        if (step < 95) {
            const int kk = (step + 1) * 32;
#pragma unroll
            for (int s = 0; s < 4; ++s) {
                ra[s] = *(const float4*)(ap + (size_t)(s * 32) * K_ + kk);
                rb[s] = *(const float4*)(bp + (size_t)(s * 32) * K_ + kk);
            }
        }
        __syncthreads();

        short8 af[4], bfr[4];
#pragma unroll
        for (int i = 0; i < 4; ++i) {
            af[i]  = *(const short8*)(Af + i * 16 * LDST);
            bfr[i] = *(const short8*)(Bf + i * 16 * LDST);
        }
#pragma unroll
        for (int mi = 0; mi < 4; ++mi)
#pragma unroll
            for (int ni = 0; ni < 4; ++ni)
                acc[mi][ni] = __builtin_amdgcn_mfma_f32_16x16x32_bf16(af[mi], bfr[ni],
                                                                      acc[mi][ni], 0, 0, 0);
    }

    float bz[4];
#pragma unroll
    for (int ni = 0; ni < 4; ++ni) bz[ni] = fcb[N0 + wc * 64 + ni * 16 + ln];

    float* nsq = normsq + R0;
#pragma unroll
    for (int mi = 0; mi < 4; ++mi) {
#pragma unroll
        for (int r = 0; r < 4; ++r) {
            float s = 0.0f;
#pragma unroll
            for (int ni = 0; ni < 4; ++ni) {
                float v = acc[mi][ni][r] + bz[ni];
                s += v * v;
            }
            s += __shfl_xor(s, 1);
            s += __shfl_xor(s, 2);
            s += __shfl_xor(s, 4);
            s += __shfl_xor(s, 8);
            if (ln == 0) atomicAdd(&nsq[wr * 64 + mi * 16 + q * 4 + r], s);
        }
    }
}

// ---------------- K2: norm1 = sqrt(normsq); per-batch softmax stats ----------------
__global__ void __launch_bounds__(256) softmax_stats_kernel(const float* __restrict__ normsq,
                                                            float* __restrict__ norm1,
                                                            float* __restrict__ bstats) {
    const int b = blockIdx.x;
    const int t = threadIdx.x;
    __shared__ float red[256];

    float vals[8];
    float mx = -1e30f;
#pragma unroll
    for (int i = 0; i < 8; ++i) {
        float v = sqrtf(normsq[b * L_ + i * 256 + t]);
        vals[i] = v;
        norm1[b * L_ + i * 256 + t] = v;
        mx = fmaxf(mx, v);
    }
    red[t] = mx;
    __syncthreads();
    for (int s = 128; s > 0; s >>= 1) {
        if (t < s) red[t] = fmaxf(red[t], red[t + s]);
        __syncthreads();
    }
    mx = red[0];
    __syncthreads();

    float sm = 0.0f;
#pragma unroll
    for (int i = 0; i < 8; ++i) sm += expf(vals[i] - mx);
    red[t] = sm;
    __syncthreads();
    for (int s = 128; s > 0; s >>= 1) {
        if (t < s) red[t] += red[t + s];
        __syncthreads();
    }
    if (t == 0) {
        bstats[b * 2 + 0] = mx;
        bstats[b * 2 + 1] = 1.0f / red[0];
    }
}

// ---------------- K3 (primary): p[b,k] = sum_l w[b,l] * trg_bf16[b,l,k] -------------
// grid 32*48: b x 16 L-chunks(128) x 3 K-chunks(1024)
__global__ void __launch_bounds__(256) pool_bf_kernel(const unsigned short* __restrict__ trgbf,
                                                      const float* __restrict__ norm1,
                                                      const float* __restrict__ bstats,
                                                      float* __restrict__ p) {
    const int t  = threadIdx.x;
    const int b  = blockIdx.x / 48;
    const int r  = blockIdx.x % 48;
    const int lc = r / 3;
    const int kc = r % 3;
    const int l0 = lc * 128;

    __shared__ float wl[128];
    if (t < 128) {
        const float mx   = bstats[b * 2 + 0];
        const float sinv = bstats[b * 2 + 1];
        wl[t] = expf(norm1[b * L_ + l0 + t] - mx) * sinv;
    }
    __syncthreads();

    const int k = kc * 1024 + t * 4;
    const unsigned short* tp = trgbf + (size_t)(b * L_ + l0) * K_ + k;
    float4 acc = {0.0f, 0.0f, 0.0f, 0.0f};
    for (int i = 0; i < 128; ++i) {
        ushort4 v = *(const ushort4*)(tp + (size_t)i * K_);
        float w = wl[i];
        acc.x += w * bf2f(v.x);
        acc.y += w * bf2f(v.y);
        acc.z += w * bf2f(v.z);
        acc.w += w * bf2f(v.w);
    }
    float* pp = p + b * K_ + k;
    atomicAdd(&pp[0], acc.x);
    atomicAdd(&pp[1], acc.y);
    atomicAdd(&pp[2], acc.z);
    atomicAdd(&pp[3], acc.w);
}

// ---------------- K3 (fallback): fp32 pool ----------------
__global__ void __launch_bounds__(256) pool_f32_kernel(const float* __restrict__ trg,
                                                       const float* __restrict__ norm1,
                                                       const float* __restrict__ bstats,
                                                       float* __restrict__ p) {
    const int t  = threadIdx.x;
    const int b  = blockIdx.x / 24;
    const int r  = blockIdx.x % 24;
    const int lc = r / 3;
    const int kc = r % 3;
    const int l0 = lc * 256;

    __shared__ float wl[256];
    const float mx   = bstats[b * 2 + 0];
    const float sinv = bstats[b * 2 + 1];
    wl[t] = expf(norm1[b * L_ + l0 + t] - mx) * sinv;
    __syncthreads();

    const int k = kc * 1024 + t * 4;
    const float* tp = trg + (size_t)b * L_ * K_ + (size_t)l0 * K_ + k;
    float4 acc = {0.0f, 0.0f, 0.0f, 0.0f};
    for (int i = 0; i < 256; ++i) {
        float4 v = *(const float4*)(tp + (size_t)i * K_);
        float w = wl[i];
        acc.x += w * v.x;
        acc.y += w * v.y;
        acc.z += w * v.z;
        acc.w += w * v.w;
    }
    float* pp = p + b * K_ + k;
    atomicAdd(&pp[0], acc.x);
    atomicAdd(&pp[1], acc.y);
    atomicAdd(&pp[2], acc.z);
    atomicAdd(&pp[3], acc.w);
}

// ---------------- K4: summ[b,h] = fc_b[h] + fc_w[h,:] . p[b,:] ----------------
__global__ void __launch_bounds__(256) summ_kernel(const float* __restrict__ fcw,
                                                   const float* __restrict__ fcb,
                                                   const float* __restrict__ p,
                                                   float* __restrict__ summ) {
    __shared__ float ps[K_];
    const int b  = blockIdx.x >> 2;
    const int hc = blockIdx.x & 3;
    const int t  = threadIdx.x;

    for (int i = t; i < K_ / 4; i += 256)
        ((float4*)ps)[i] = ((const float4*)(p + (size_t)b * K_))[i];
    __syncthreads();

    const int h = hc * 256 + t;
    const float4* wrow = (const float4*)(fcw + (size_t)h * K_);
    float acc = fcb[h];
    for (int i = 0; i < K_ / 4; ++i) {
        float4 wv = wrow[i];
        float4 pv = ((const float4*)ps)[i];
        acc += wv.x * pv.x + wv.y * pv.y + wv.z * pv.z + wv.w * pv.w;
    }
    summ[b * H_ + h] = acc;
}

extern "C" void kernel_launch(void* const* d_in, const int* in_sizes, int n_in,
                              void* d_out, int out_size, void* d_ws, size_t ws_size,
                              hipStream_t stream) {
    (void)in_sizes; (void)n_in; (void)out_size;
    const float* trg = (const float*)d_in[0];
    // d_in[1] = src, unused (n_layers == 0)
    const float* fcw = (const float*)d_in[2];
    const float* fcb = (const float*)d_in[3];

    float* out   = (float*)d_out;
    float* summ  = out;            // [32*1024]
    float* norm1 = out + B_ * H_;  // [32*2048]

    const size_t trgbf_elems = (size_t)M_ * K_;      // 201,326,592
    const size_t fcwbf_elems = (size_t)H_ * K_;      // 3,145,728
    const size_t acc_bytes   = (size_t)(M_ + B_ * K_ + 64) * sizeof(float);
    const size_t need = (trgbf_elems + fcwbf_elems) * sizeof(unsigned short) + acc_bytes;

    if (ws_size >= need) {
        // primary path: pre-convert to bf16, pipelined global_load_lds GEMM
        unsigned short* trgbf = (unsigned short*)d_ws;
        unsigned short* fcwbf = trgbf + trgbf_elems;
        float* normsq = (float*)(fcwbf + fcwbf_elems);
        float* p      = normsq + M_;
        float* bstats = p + B_ * K_;

        hipMemsetAsync(normsq, 0, acc_bytes, stream);
        hipLaunchKernelGGL(convert_bf16_kernel, dim3(16384), dim3(256), 0, stream,
                           trg, trgbf, (int)(trgbf_elems / 8));
        hipLaunchKernelGGL(convert_bf16_kernel, dim3(1536), dim3(256), 0, stream,
                           fcw, fcwbf, (int)(fcwbf_elems / 8));
        hipLaunchKernelGGL(gemm_norm_bf_kernel, dim3(2048), dim3(512), 0, stream,
                           trgbf, fcwbf, fcb, normsq);
        hipLaunchKernelGGL(softmax_stats_kernel, dim3(B_), dim3(256), 0, stream,
                           normsq, norm1, bstats);
        hipLaunchKernelGGL(pool_bf_kernel, dim3(B_ * 48), dim3(256), 0, stream,
                           trgbf, norm1, bstats, p);
        hipLaunchKernelGGL(summ_kernel, dim3(B_ * 4), dim3(256), 0, stream,
                           fcw, fcb, p, summ);
    } else {
        // fallback: fp32-input GEMM with in-kernel conversion
        float* normsq = (float*)d_ws;
        float* p      = normsq + M_;
        float* bstats = p + B_ * K_;

        hipMemsetAsync(d_ws, 0, acc_bytes, stream);
        hipLaunchKernelGGL(gemm_norm_f32_kernel, dim3(4096), dim3(256), 0, stream,
                           trg, fcw, fcb, normsq);
        hipLaunchKernelGGL(softmax_stats_kernel, dim3(B_), dim3(256), 0, stream,
                           normsq, norm1, bstats);
        hipLaunchKernelGGL(pool_f32_kernel, dim3(B_ * 24), dim3(256), 0, stream,
                           trg, norm1, bstats, p);
        hipLaunchKernelGGL(summ_kernel, dim3(B_ * 4), dim3(256), 0, stream,
                           fcw, fcb, p, summ);
    }
}

// Round 13
// 1664.178 us; speedup vs baseline: 1.3193x; 1.3193x over previous
//
#include <hip/hip_runtime.h>
#include <hip/hip_bf16.h>

// Problem: B=32, L=2048, H=1024, K=3H=3072, M=B*L=65536
// ref: t = trg @ fc_w^T + fc_b  [M, H]
//      norm1 = ||t||_2 over H   [B, L]
//      w = softmax(norm1, axis=L)
//      summ = sum_l w * t = fc_w @ (sum_l w*trg) + fc_b   (since sum_l w == 1)
// out = concat(summ [32*1024], norm1 [32*2048]) fp32

#define B_ 32
#define L_ 2048
#define H_ 1024
#define K_ 3072
#define M_ 65536

typedef __attribute__((ext_vector_type(8))) short short8;
typedef __attribute__((ext_vector_type(4))) float floatx4;

__device__ __forceinline__ unsigned int pack_bf16x2(float a, float b) {
    __hip_bfloat162 h = __float22bfloat162_rn(make_float2(a, b));
    return *reinterpret_cast<unsigned int*>(&h);
}

__device__ __forceinline__ float bf2f(unsigned short u) {
    return __uint_as_float(((unsigned int)u) << 16);
}

// async global->LDS, 16B per lane; lds dest is wave-uniform base + lane*16
__device__ __forceinline__ void gl_lds16(const unsigned short* g, unsigned short* l) {
    __builtin_amdgcn_global_load_lds(
        (const __attribute__((address_space(1))) unsigned int*)g,
        (__attribute__((address_space(3))) unsigned int*)l, 16, 0, 0);
}

// ---------------- K0: fp32 -> bf16 convert (grid-stride, 8 elems/thread/iter) --------
__global__ void __launch_bounds__(256) convert_bf16_kernel(const float* __restrict__ in,
                                                           unsigned short* __restrict__ out,
                                                           int n8) {
    int i = blockIdx.x * blockDim.x + threadIdx.x;
    const int stride = gridDim.x * blockDim.x;
    for (; i < n8; i += stride) {
        const float4* pp = (const float4*)in + (size_t)i * 2;
        float4 a = pp[0], b = pp[1];
        uint4 r;
        r.x = pack_bf16x2(a.x, a.y);
        r.y = pack_bf16x2(a.z, a.w);
        r.z = pack_bf16x2(b.x, b.y);
        r.w = pack_bf16x2(b.z, b.w);
        ((uint4*)out)[i] = r;
    }
}

// ---------------- K1 (primary): m97-structure bf16 GEMM, BK=64 + validated swizzle ---
// R11 post-mortem: the counted-vmcnt 512-thr pipeline halved occupancy (42->24%)
// and exposed load latency at every barrier (MfmaUtil 34->17.5%). Reverting to the
// PROVEN baseline structure (256 thr, 128x128 tile, gl_lds16 A+B, 2-syncthreads,
// compiler-scheduled waits, 4 blocks/CU implicit overlap) and keeping only the
// hardware-validated piece: both-sides XOR swizzle (conflicts 5.0e7 -> 0 measured).
// Swizzle requires 128B rows -> BK=64 (also halves barrier count: 96 -> 48 pairs).
// LDS[row][s] = global chunk s^(row&7); reads fetch phys slot (kk*4+q)^(ln&7).
__global__ void __launch_bounds__(256, 4) gemm_norm_bf_kernel(
        const unsigned short* __restrict__ A,   // trg bf16 [M_, K_]
        const unsigned short* __restrict__ Bw,  // fcw bf16 [H_, K_]
        const float* __restrict__ fcb,          // [H_]
        float* __restrict__ normsq) {
    __shared__ unsigned short As[128 * 64];   // 16KB, 128B rows
    __shared__ unsigned short Bs[128 * 64];   // 16KB

    const int tid = threadIdx.x;
    const int bid = blockIdx.x;
    const int group  = bid >> 6;
    const int lane64 = bid & 63;
    const int xcd    = lane64 & 7;
    const int nblk   = lane64 >> 3;   // 0..7
    const int mblk   = group * 8 + xcd;
    const int R0 = mblk * 128;
    const int N0 = nblk * 128;

    const int wv = tid >> 6, lane = tid & 63;
    const int wr = wv >> 1, wc = wv & 1;
    const int q = lane >> 4, ln = lane & 15;

    // staging: each wave stages rows [wv*32, wv*32+32) of A and B as 4x 8-row 1KB
    // chunks each. LDS dest linear; swizzle via permuted GLOBAL source chunk
    // (both-sides rule): lane l -> row rin=l>>3, lds slot l&7, global chunk (l&7)^rin.
    const int rin = lane >> 3;
    const int slg = (lane & 7) ^ rin;
    const unsigned short* agp = A  + (size_t)(R0 + wv * 32 + rin) * K_ + slg * 8;
    const unsigned short* bgp = Bw + (size_t)(N0 + wv * 32 + rin) * K_ + slg * 8;
    unsigned short* alds = &As[wv * 32 * 64];
    unsigned short* blds = &Bs[wv * 32 * 64];

    // frag read bases: row = {wr|wc}*64 + mi*16 + ln (row&7 == ln&7);
    // chunk kk*4+q lives at phys slot (kk*4+q)^(ln&7)
    const int sw = ln & 7;
    const unsigned short* Af0 = &As[(wr * 64 + ln) * 64 + ((q ^ sw) * 8)];
    const unsigned short* Af1 = &As[(wr * 64 + ln) * 64 + (((4 + q) ^ sw) * 8)];
    const unsigned short* Bf0 = &Bs[(wc * 64 + ln) * 64 + ((q ^ sw) * 8)];
    const unsigned short* Bf1 = &Bs[(wc * 64 + ln) * 64 + (((4 + q) ^ sw) * 8)];

    floatx4 acc[4][4] = {};

    // prologue: stage tile 0 (k=0)
#pragma unroll
    for (int j = 0; j < 4; ++j) {
        gl_lds16(agp + (size_t)(j * 8) * K_, alds + j * 512);
        gl_lds16(bgp + (size_t)(j * 8) * K_, blds + j * 512);
    }

    for (int step = 0; step < 48; ++step) {
        __syncthreads();  // barrier drains vmcnt: this step's tile resident in LDS

        // kk=0 sub-phase: 8 frag reads, 16 MFMA (frags die here -> regs reused)
        short8 a0[4], b0[4];
#pragma unroll
        for (int i = 0; i < 4; ++i) {
            a0[i] = *(const short8*)(Af0 + i * 1024);
            b0[i] = *(const short8*)(Bf0 + i * 1024);
        }
#pragma unroll
        for (int mi = 0; mi < 4; ++mi)
#pragma unroll
            for (int ni = 0; ni < 4; ++ni)
                acc[mi][ni] = __builtin_amdgcn_mfma_f32_16x16x32_bf16(a0[mi], b0[ni],
                                                                      acc[mi][ni], 0, 0, 0);

        // kk=1 frag reads must precede the barrier (tile overwritten after it)
        short8 a1[4], b1[4];
#pragma unroll
        for (int i = 0; i < 4; ++i) {
            a1[i] = *(const short8*)(Af1 + i * 1024);
            b1[i] = *(const short8*)(Bf1 + i * 1024);
        }
        __syncthreads();  // all waves done reading LDS before next-step overwrite

        if (step < 47) {
            const int kb = (step + 1) * 64;
#pragma unroll
            for (int j = 0; j < 4; ++j) {
                gl_lds16(agp + (size_t)(j * 8) * K_ + kb, alds + j * 512);
                gl_lds16(bgp + (size_t)(j * 8) * K_ + kb, blds + j * 512);
            }
        }

#pragma unroll
        for (int mi = 0; mi < 4; ++mi)
#pragma unroll
            for (int ni = 0; ni < 4; ++ni)
                acc[mi][ni] = __builtin_amdgcn_mfma_f32_16x16x32_bf16(a1[mi], b1[ni],
                                                                      acc[mi][ni], 0, 0, 0);
    }

    // epilogue: add bias, per-row sum of squares over this block's 128 cols
    // D layout: col = ln, row = q*4 + reg  (baseline-proven)
    float bz[4];
#pragma unroll
    for (int ni = 0; ni < 4; ++ni) bz[ni] = fcb[N0 + wc * 64 + ni * 16 + ln];

    float* nsq = normsq + R0 + wr * 64;
#pragma unroll
    for (int mi = 0; mi < 4; ++mi) {
#pragma unroll
        for (int r = 0; r < 4; ++r) {
            float s = 0.0f;
#pragma unroll
            for (int ni = 0; ni < 4; ++ni) {
                float v = acc[mi][ni][r] + bz[ni];
                s += v * v;
            }
            s += __shfl_xor(s, 1);
            s += __shfl_xor(s, 2);
            s += __shfl_xor(s, 4);
            s += __shfl_xor(s, 8);
            if (ln == 0) atomicAdd(&nsq[mi * 16 + q * 4 + r], s);
        }
    }
}

// ---------------- K1 (fallback): fp32-input GEMM with in-kernel convert -------------
#define LDST 40
__global__ void __launch_bounds__(256) gemm_norm_f32_kernel(const float* __restrict__ trg,
                                                            const float* __restrict__ fcw,
                                                            const float* __restrict__ fcb,
                                                            float* __restrict__ normsq) {
    __shared__ unsigned short As[128 * LDST];
    __shared__ unsigned short Bs[128 * LDST];

    const int tid  = threadIdx.x;
    const int bid  = blockIdx.x;
    const int group  = bid >> 6;
    const int lane64 = bid & 63;
    const int nblk   = lane64 >> 3;
    const int mblk   = group * 8 + (lane64 & 7);
    const int R0   = mblk * 128;
    const int N0   = nblk * 128;
    const int wv   = tid >> 6;
    const int lane = tid & 63;
    const int wr   = wv >> 1;
    const int wc   = wv & 1;
    const int q    = lane >> 4;
    const int ln   = lane & 15;

    floatx4 acc[4][4] = {};

    const int srow = tid >> 3;
    const int skc  = tid & 7;
    const float* ap = trg + (size_t)(R0 + srow) * K_ + skc * 4;
    const float* bp = fcw + (size_t)(N0 + srow) * K_ + skc * 4;
    unsigned short* AsW = &As[srow * LDST + skc * 4];
    unsigned short* BsW = &Bs[srow * LDST + skc * 4];

    const unsigned short* Af = &As[(wr * 64 + ln) * LDST + q * 8];
    const unsigned short* Bf = &Bs[(wc * 64 + ln) * LDST + q * 8];

    float4 ra[4], rb[4];
#pragma unroll
    for (int s = 0; s < 4; ++s) {
        ra[s] = *(const float4*)(ap + (size_t)(s * 32) * K_);
        rb[s] = *(const float4*)(bp + (size_t)(s * 32) * K_);
    }

    for (int step = 0; step < 96; ++step) {
        __syncthreads();
#pragma unroll
        for (int s = 0; s < 4; ++s) {
            uint2 ua, ub;
            ua.x = pack_bf16x2(ra[s].x, ra[s].y);
            ua.y = pack_bf16x2(ra[s].z, ra[s].w);
            ub.x = pack_bf16x2(rb[s].x, rb[s].y);
            ub.y = pack_bf16x2(rb[s].z, rb[s].w);
            *(uint2*)(AsW + s * 32 * LDST) = ua;
            *(uint2*)(BsW + s * 32 * LDST) = ub;
        }
        if (step < 95) {
            const int kk = (step + 1) * 32;
#pragma unroll
            for (int s = 0; s < 4; ++s) {
                ra[s] = *(const float4*)(ap + (size_t)(s * 32) * K_ + kk);
                rb[s] = *(const float4*)(bp + (size_t)(s * 32) * K_ + kk);
            }
        }
        __syncthreads();

        short8 af[4], bfr[4];
#pragma unroll
        for (int i = 0; i < 4; ++i) {
            af[i]  = *(const short8*)(Af + i * 16 * LDST);
            bfr[i] = *(const short8*)(Bf + i * 16 * LDST);
        }
#pragma unroll
        for (int mi = 0; mi < 4; ++mi)
#pragma unroll
            for (int ni = 0; ni < 4; ++ni)
                acc[mi][ni] = __builtin_amdgcn_mfma_f32_16x16x32_bf16(af[mi], bfr[ni],
                                                                      acc[mi][ni], 0, 0, 0);
    }

    float bz[4];
#pragma unroll
    for (int ni = 0; ni < 4; ++ni) bz[ni] = fcb[N0 + wc * 64 + ni * 16 + ln];

    float* nsq = normsq + R0;
#pragma unroll
    for (int mi = 0; mi < 4; ++mi) {
#pragma unroll
        for (int r = 0; r < 4; ++r) {
            float s = 0.0f;
#pragma unroll
            for (int ni = 0; ni < 4; ++ni) {
                float v = acc[mi][ni][r] + bz[ni];
                s += v * v;
            }
            s += __shfl_xor(s, 1);
            s += __shfl_xor(s, 2);
            s += __shfl_xor(s, 4);
            s += __shfl_xor(s, 8);
            if (ln == 0) atomicAdd(&nsq[wr * 64 + mi * 16 + q * 4 + r], s);
        }
    }
}

// ---------------- K2: norm1 = sqrt(normsq); per-batch softmax stats ----------------
__global__ void __launch_bounds__(256) softmax_stats_kernel(const float* __restrict__ normsq,
                                                            float* __restrict__ norm1,
                                                            float* __restrict__ bstats) {
    const int b = blockIdx.x;
    const int t = threadIdx.x;
    __shared__ float red[256];

    float vals[8];
    float mx = -1e30f;
#pragma unroll
    for (int i = 0; i < 8; ++i) {
        float v = sqrtf(normsq[b * L_ + i * 256 + t]);
        vals[i] = v;
        norm1[b * L_ + i * 256 + t] = v;
        mx = fmaxf(mx, v);
    }
    red[t] = mx;
    __syncthreads();
    for (int s = 128; s > 0; s >>= 1) {
        if (t < s) red[t] = fmaxf(red[t], red[t + s]);
        __syncthreads();
    }
    mx = red[0];
    __syncthreads();

    float sm = 0.0f;
#pragma unroll
    for (int i = 0; i < 8; ++i) sm += expf(vals[i] - mx);
    red[t] = sm;
    __syncthreads();
    for (int s = 128; s > 0; s >>= 1) {
        if (t < s) red[t] += red[t + s];
        __syncthreads();
    }
    if (t == 0) {
        bstats[b * 2 + 0] = mx;
        bstats[b * 2 + 1] = 1.0f / red[0];
    }
}

// ---------------- K3 (primary): p[b,k] = sum_l w[b,l] * trg_bf16[b,l,k] -------------
// grid 32*48: b x 16 L-chunks(128) x 3 K-chunks(1024)
__global__ void __launch_bounds__(256) pool_bf_kernel(const unsigned short* __restrict__ trgbf,
                                                      const float* __restrict__ norm1,
                                                      const float* __restrict__ bstats,
                                                      float* __restrict__ p) {
    const int t  = threadIdx.x;
    const int b  = blockIdx.x / 48;
    const int r  = blockIdx.x % 48;
    const int lc = r / 3;
    const int kc = r % 3;
    const int l0 = lc * 128;

    __shared__ float wl[128];
    if (t < 128) {
        const float mx   = bstats[b * 2 + 0];
        const float sinv = bstats[b * 2 + 1];
        wl[t] = expf(norm1[b * L_ + l0 + t] - mx) * sinv;
    }
    __syncthreads();

    const int k = kc * 1024 + t * 4;
    const unsigned short* tp = trgbf + (size_t)(b * L_ + l0) * K_ + k;
    float4 acc = {0.0f, 0.0f, 0.0f, 0.0f};
    for (int i = 0; i < 128; ++i) {
        ushort4 v = *(const ushort4*)(tp + (size_t)i * K_);
        float w = wl[i];
        acc.x += w * bf2f(v.x);
        acc.y += w * bf2f(v.y);
        acc.z += w * bf2f(v.z);
        acc.w += w * bf2f(v.w);
    }
    float* pp = p + b * K_ + k;
    atomicAdd(&pp[0], acc.x);
    atomicAdd(&pp[1], acc.y);
    atomicAdd(&pp[2], acc.z);
    atomicAdd(&pp[3], acc.w);
}

// ---------------- K3 (fallback): fp32 pool ----------------
__global__ void __launch_bounds__(256) pool_f32_kernel(const float* __restrict__ trg,
                                                       const float* __restrict__ norm1,
                                                       const float* __restrict__ bstats,
                                                       float* __restrict__ p) {
    const int t  = threadIdx.x;
    const int b  = blockIdx.x / 24;
    const int r  = blockIdx.x % 24;
    const int lc = r / 3;
    const int kc = r % 3;
    const int l0 = lc * 256;

    __shared__ float wl[256];
    const float mx   = bstats[b * 2 + 0];
    const float sinv = bstats[b * 2 + 1];
    wl[t] = expf(norm1[b * L_ + l0 + t] - mx) * sinv;
    __syncthreads();

    const int k = kc * 1024 + t * 4;
    const float* tp = trg + (size_t)b * L_ * K_ + (size_t)l0 * K_ + k;
    float4 acc = {0.0f, 0.0f, 0.0f, 0.0f};
    for (int i = 0; i < 256; ++i) {
        float4 v = *(const float4*)(tp + (size_t)i * K_);
        float w = wl[i];
        acc.x += w * v.x;
        acc.y += w * v.y;
        acc.z += w * v.z;
        acc.w += w * v.w;
    }
    float* pp = p + b * K_ + k;
    atomicAdd(&pp[0], acc.x);
    atomicAdd(&pp[1], acc.y);
    atomicAdd(&pp[2], acc.z);
    atomicAdd(&pp[3], acc.w);
}

// ---------------- K4: summ[b,h] = fc_b[h] + fc_w[h,:] . p[b,:] ----------------
__global__ void __launch_bounds__(256) summ_kernel(const float* __restrict__ fcw,
                                                   const float* __restrict__ fcb,
                                                   const float* __restrict__ p,
                                                   float* __restrict__ summ) {
    __shared__ float ps[K_];
    const int b  = blockIdx.x >> 2;
    const int hc = blockIdx.x & 3;
    const int t  = threadIdx.x;

    for (int i = t; i < K_ / 4; i += 256)
        ((float4*)ps)[i] = ((const float4*)(p + (size_t)b * K_))[i];
    __syncthreads();

    const int h = hc * 256 + t;
    const float4* wrow = (const float4*)(fcw + (size_t)h * K_);
    float acc = fcb[h];
    for (int i = 0; i < K_ / 4; ++i) {
        float4 wv = wrow[i];
        float4 pv = ((const float4*)ps)[i];
        acc += wv.x * pv.x + wv.y * pv.y + wv.z * pv.z + wv.w * pv.w;
    }
    summ[b * H_ + h] = acc;
}

extern "C" void kernel_launch(void* const* d_in, const int* in_sizes, int n_in,
                              void* d_out, int out_size, void* d_ws, size_t ws_size,
                              hipStream_t stream) {
    (void)in_sizes; (void)n_in; (void)out_size;
    const float* trg = (const float*)d_in[0];
    // d_in[1] = src, unused (n_layers == 0)
    const float* fcw = (const float*)d_in[2];
    const float* fcb = (const float*)d_in[3];

    float* out   = (float*)d_out;
    float* summ  = out;            // [32*1024]
    float* norm1 = out + B_ * H_;  // [32*2048]

    const size_t trgbf_elems = (size_t)M_ * K_;      // 201,326,592
    const size_t fcwbf_elems = (size_t)H_ * K_;      // 3,145,728
    const size_t acc_bytes   = (size_t)(M_ + B_ * K_ + 64) * sizeof(float);
    const size_t need = (trgbf_elems + fcwbf_elems) * sizeof(unsigned short) + acc_bytes;

    if (ws_size >= need) {
        // primary path: pre-convert to bf16, swizzled gl_lds16 GEMM (m97 structure)
        unsigned short* trgbf = (unsigned short*)d_ws;
        unsigned short* fcwbf = trgbf + trgbf_elems;
        float* normsq = (float*)(fcwbf + fcwbf_elems);
        float* p      = normsq + M_;
        float* bstats = p + B_ * K_;

        hipMemsetAsync(normsq, 0, acc_bytes, stream);
        hipLaunchKernelGGL(convert_bf16_kernel, dim3(16384), dim3(256), 0, stream,
                           trg, trgbf, (int)(trgbf_elems / 8));
        hipLaunchKernelGGL(convert_bf16_kernel, dim3(1536), dim3(256), 0, stream,
                           fcw, fcwbf, (int)(fcwbf_elems / 8));
        hipLaunchKernelGGL(gemm_norm_bf_kernel, dim3(4096), dim3(256), 0, stream,
                           trgbf, fcwbf, fcb, normsq);
        hipLaunchKernelGGL(softmax_stats_kernel, dim3(B_), dim3(256), 0, stream,
                           normsq, norm1, bstats);
        hipLaunchKernelGGL(pool_bf_kernel, dim3(B_ * 48), dim3(256), 0, stream,
                           trgbf, norm1, bstats, p);
        hipLaunchKernelGGL(summ_kernel, dim3(B_ * 4), dim3(256), 0, stream,
                           fcw, fcb, p, summ);
    } else {
        // fallback: fp32-input GEMM with in-kernel conversion
        float* normsq = (float*)d_ws;
        float* p      = normsq + M_;
        float* bstats = p + B_ * K_;

        hipMemsetAsync(d_ws, 0, acc_bytes, stream);
        hipLaunchKernelGGL(gemm_norm_f32_kernel, dim3(4096), dim3(256), 0, stream,
                           trg, fcw, fcb, normsq);
        hipLaunchKernelGGL(softmax_stats_kernel, dim3(B_), dim3(256), 0, stream,
                           normsq, norm1, bstats);
        hipLaunchKernelGGL(pool_f32_kernel, dim3(B_ * 24), dim3(256), 0, stream,
                           trg, norm1, bstats, p);
        hipLaunchKernelGGL(summ_kernel, dim3(B_ * 4), dim3(256), 0, stream,
                           fcw, fcb, p, summ);
    }
}